// Round 1
// baseline (461.930 us; speedup 1.0000x reference)
//
#include <hip/hip_runtime.h>

#define BATCH   128
#define CIN     8
#define HW      128
#define COUT    64
#define OHW     126
#define NGROUPS 16
#define CPG     4
#define STRIPS_A 21
#define ROWS_A   6
#define TILE_A   (ROWS_A + 2)
#define LDSW     132
#define PH       31
#define GN_EPS   1e-5f

// ---------------- Pass A: conv + per-(b,g) partial stats ----------------
__global__ __launch_bounds__(256) void conv_stats(
    const float* __restrict__ x, const float* __restrict__ w,
    const float* __restrict__ bias, float* __restrict__ part)
{
    __shared__ float sx[CIN][TILE_A][LDSW];
    __shared__ float red[4][NGROUPS][2];
    const int strip = blockIdx.x;
    const int b     = blockIdx.y;
    const int tid   = threadIdx.x;
    const int wave  = tid >> 6;
    const int lane  = tid & 63;
    const int r0    = strip * ROWS_A;

    // stage input rows r0..r0+7 for all 8 cin (cols 128..131 of LDS left as garbage, masked later)
    {
        const float* xb = x + (size_t)b * CIN * HW * HW;
        for (int idx = tid; idx < CIN * TILE_A * (HW / 4); idx += 256) {
            int cin = idx / (TILE_A * 32);
            int rem = idx % (TILE_A * 32);
            int row = rem >> 5;
            int c4  = (rem & 31) << 2;
            float4 v = *(const float4*)&xb[(cin * HW + (r0 + row)) * HW + c4];
            float* d = &sx[cin][row][c4];
            d[0] = v.x; d[1] = v.y; d[2] = v.z; d[3] = v.w;
        }
    }

    // per-lane channel weights (channel = lane)
    float wreg[3][3][CIN];
    {
        const float* wc = w + lane * (CIN * 9);
        #pragma unroll
        for (int cin = 0; cin < CIN; ++cin)
            #pragma unroll
            for (int dy = 0; dy < 3; ++dy)
                #pragma unroll
                for (int dx = 0; dx < 3; ++dx)
                    wreg[dy][dx][cin] = wc[cin * 9 + dy * 3 + dx];
    }
    const float bs = bias[lane];
    __syncthreads();

    float s1 = 0.f, s2 = 0.f;
    for (int iter = wave; iter < ROWS_A * 16; iter += 4) {
        const int row = iter >> 4;        // 0..5
        const int cb  = (iter & 15) << 3; // 0,8,...,120
        float acc[8];
        #pragma unroll
        for (int p = 0; p < 8; ++p) acc[p] = bs;
        #pragma unroll
        for (int dy = 0; dy < 3; ++dy) {
            #pragma unroll
            for (int cin = 0; cin < CIN; ++cin) {
                const float* srow = &sx[cin][row + dy][cb];
                float4 i0 = *(const float4*)&srow[0];
                float4 i1 = *(const float4*)&srow[4];
                float4 i2 = *(const float4*)&srow[8];
                float in[12] = {i0.x,i0.y,i0.z,i0.w, i1.x,i1.y,i1.z,i1.w,
                                i2.x,i2.y,i2.z,i2.w};
                #pragma unroll
                for (int dx = 0; dx < 3; ++dx)
                    #pragma unroll
                    for (int p = 0; p < 8; ++p)
                        acc[p] = fmaf(in[dx + p], wreg[dy][dx][cin], acc[p]);
            }
        }
        const int nvalid = (OHW - cb) < 8 ? (OHW - cb) : 8; // 8 except cb=120 -> 6
        #pragma unroll
        for (int p = 0; p < 8; ++p) {
            if (p < nvalid) { s1 += acc[p]; s2 = fmaf(acc[p], acc[p], s2); }
        }
    }

    // reduce across the 4 channels of each group (lanes c^1, c^2 are same group)
    s1 += __shfl_xor(s1, 1); s1 += __shfl_xor(s1, 2);
    s2 += __shfl_xor(s2, 1); s2 += __shfl_xor(s2, 2);
    if ((lane & 3) == 0) {
        red[wave][lane >> 2][0] = s1;
        red[wave][lane >> 2][1] = s2;
    }
    __syncthreads();
    if (tid < 32) {
        int g = tid >> 1, which = tid & 1;
        float v = red[0][g][which] + red[1][g][which] + red[2][g][which] + red[3][g][which];
        part[(((size_t)b * STRIPS_A + strip) * NGROUPS + g) * 2 + which] = v;
    }
}

// ---------------- Pass A2: fold stats into per-(b,c) affine A,B ----------------
__global__ __launch_bounds__(256) void finalize_stats(
    const float* __restrict__ part, const float* __restrict__ gnw,
    const float* __restrict__ gnb, const float* __restrict__ scale,
    float* __restrict__ Aarr, float* __restrict__ Barr)
{
    int t = blockIdx.x * 256 + threadIdx.x;
    if (t >= BATCH * NGROUPS) return;
    int b = t >> 4, g = t & 15;
    float s1 = 0.f, s2 = 0.f;
    for (int s = 0; s < STRIPS_A; ++s) {
        s1 += part[(((size_t)b * STRIPS_A + s) * NGROUPS + g) * 2 + 0];
        s2 += part[(((size_t)b * STRIPS_A + s) * NGROUPS + g) * 2 + 1];
    }
    const float invN = 1.f / (float)(CPG * OHW * OHW);
    float mean = s1 * invN;
    float var  = s2 * invN - mean * mean;
    float rstd = rsqrtf(var + GN_EPS);
    #pragma unroll
    for (int i = 0; i < CPG; ++i) {
        int c = g * CPG + i;
        float A  = rstd * gnw[c] * scale[c];
        float Bv = (gnb[c] - mean * rstd * gnw[c]) * scale[c];
        Aarr[b * COUT + c] = A;
        Barr[b * COUT + c] = Bv;
    }
}

// ---------------- Pass B: conv + affine + maxpool + clamp ----------------
__global__ __launch_bounds__(256) void conv_pool(
    const float* __restrict__ x, const float* __restrict__ w,
    const float* __restrict__ bias, const float* __restrict__ Aarr,
    const float* __restrict__ Barr, float* __restrict__ out)
{
    __shared__ float sx[CIN][6][LDSW];
    __shared__ float pl[4][COUT][2];
    const int prow = blockIdx.x;  // 0..30
    const int b    = blockIdx.y;
    const int tid  = threadIdx.x;
    const int wave = tid >> 6;
    const int lane = tid & 63;
    const int r0   = prow * 4;

    {
        const float* xb = x + (size_t)b * CIN * HW * HW;
        for (int idx = tid; idx < CIN * 6 * (HW / 4); idx += 256) {
            int cin = idx / (6 * 32);
            int rem = idx % (6 * 32);
            int row = rem >> 5;
            int c4  = (rem & 31) << 2;
            float4 v = *(const float4*)&xb[(cin * HW + (r0 + row)) * HW + c4];
            float* d = &sx[cin][row][c4];
            d[0] = v.x; d[1] = v.y; d[2] = v.z; d[3] = v.w;
        }
    }

    float wreg[3][3][CIN];
    {
        const float* wc = w + lane * (CIN * 9);
        #pragma unroll
        for (int cin = 0; cin < CIN; ++cin)
            #pragma unroll
            for (int dy = 0; dy < 3; ++dy)
                #pragma unroll
                for (int dx = 0; dx < 3; ++dx)
                    wreg[dy][dx][cin] = wc[cin * 9 + dy * 3 + dx];
    }
    const float bs = bias[lane];
    const float Ac = Aarr[b * COUT + lane];
    const float Bc = Barr[b * COUT + lane];
    __syncthreads();

    const int row = wave; // conv output row r0+wave, tile row index = wave
    for (int cg = 0; cg < 16; ++cg) {
        const int cb = cg << 3;
        float acc[8];
        #pragma unroll
        for (int p = 0; p < 8; ++p) acc[p] = bs;
        #pragma unroll
        for (int dy = 0; dy < 3; ++dy) {
            #pragma unroll
            for (int cin = 0; cin < CIN; ++cin) {
                const float* srow = &sx[cin][row + dy][cb];
                float4 i0 = *(const float4*)&srow[0];
                float4 i1 = *(const float4*)&srow[4];
                float4 i2 = *(const float4*)&srow[8];
                float in[12] = {i0.x,i0.y,i0.z,i0.w, i1.x,i1.y,i1.z,i1.w,
                                i2.x,i2.y,i2.z,i2.w};
                #pragma unroll
                for (int dx = 0; dx < 3; ++dx)
                    #pragma unroll
                    for (int p = 0; p < 8; ++p)
                        acc[p] = fmaf(in[dx + p], wreg[dy][dx][cin], acc[p]);
            }
        }
        // affine + horizontal 4-max
        float v0 = acc[0] * Ac + Bc;
        float v1 = acc[1] * Ac + Bc;
        float v2 = acc[2] * Ac + Bc;
        float v3 = acc[3] * Ac + Bc;
        float v4 = acc[4] * Ac + Bc;
        float v5 = acc[5] * Ac + Bc;
        float v6 = acc[6] * Ac + Bc;
        float v7 = acc[7] * Ac + Bc;
        float m0 = fmaxf(fmaxf(v0, v1), fmaxf(v2, v3));
        float m1 = fmaxf(fmaxf(v4, v5), fmaxf(v6, v7));
        pl[wave][lane][0] = m0;
        pl[wave][lane][1] = m1;
        __syncthreads();
        if (tid < 128) {
            int c = tid >> 1, which = tid & 1;
            float m = fmaxf(fmaxf(pl[0][c][which], pl[1][c][which]),
                            fmaxf(pl[2][c][which], pl[3][c][which]));
            m = fminf(fmaxf(m, 0.f), 1.f);
            int pcol = cg * 2 + which;
            if (pcol < PH)
                out[(((size_t)b * COUT + c) * PH + prow) * PH + pcol] = m;
        }
        __syncthreads();
    }
}

extern "C" void kernel_launch(void* const* d_in, const int* in_sizes, int n_in,
                              void* d_out, int out_size, void* d_ws, size_t ws_size,
                              hipStream_t stream)
{
    const float* x   = (const float*)d_in[0];
    const float* w   = (const float*)d_in[1];
    const float* cbv = (const float*)d_in[2];
    const float* gnw = (const float*)d_in[3];
    const float* gnb = (const float*)d_in[4];
    const float* sc  = (const float*)d_in[5];
    float* out = (float*)d_out;

    float* part = (float*)d_ws;                               // 128*21*16*2 = 86016 f32
    float* Aarr = part + (size_t)BATCH * STRIPS_A * NGROUPS * 2;
    float* Barr = Aarr + (size_t)BATCH * COUT;

    conv_stats<<<dim3(STRIPS_A, BATCH), 256, 0, stream>>>(x, w, cbv, part);
    finalize_stats<<<dim3(8), 256, 0, stream>>>(part, gnw, gnb, sc, Aarr, Barr);
    conv_pool<<<dim3(PH, BATCH), 256, 0, stream>>>(x, w, cbv, Aarr, Barr, out);
}

// Round 2
// 84.304 us; speedup vs baseline: 5.4793x; 5.4793x over previous
//
#include <hip/hip_runtime.h>

typedef __attribute__((ext_vector_type(8))) short short8v;
typedef __attribute__((ext_vector_type(4))) float f32x4;
typedef __attribute__((ext_vector_type(4))) int i32x4;

#define BATCH 128
#define CIN 8
#define HW 128
#define COUT 64
#define OHW 126
#define NG 16
#define PH 31
#define GN_EPS 1e-5f

#define ROWS_A 8
#define STRIPS_A 16
#define INROWS_A 11   // 10 real + 1 zero pad (for g=3 reads)
#define INROWS_B 7    // 6 real + 1 zero pad
#define ACOLS 132

static __device__ __forceinline__ short f2bf(float f) {
    unsigned u = __float_as_uint(f);
    unsigned r = (u + 0x7fffu + ((u >> 16) & 1u)) >> 16;
    return (short)r;
}

// ---- prep: pack weights into MFMA B-fragment order, bf16 ----
// Bpack[((dx*4+nt)*64+lane)*8 + j] = w[nt*16+(lane&15)][cin=j][dy=lane>>4][dx], 0 for dy==3
__global__ __launch_bounds__(256) void prep_weights(const float* __restrict__ w,
                                                    short* __restrict__ Bpack)
{
    for (int e = threadIdx.x; e < 3 * 4 * 64; e += 256) {
        int dx = e >> 8;
        int nt = (e >> 6) & 3;
        int l  = e & 63;
        int i = l & 15, g = l >> 4;
        int n = nt * 16 + i;
        #pragma unroll
        for (int j = 0; j < 8; ++j) {
            float v = (g < 3) ? w[((n * CIN + j) * 3 + g) * 3 + dx] : 0.f;
            Bpack[e * 8 + j] = f2bf(v);
        }
    }
}

// ---- pass A: bf16-MFMA conv + per-(b,group) partial stats ----
__global__ __launch_bounds__(256, 4) void conv_stats(
    const float* __restrict__ x, const short* __restrict__ Bpack,
    const float* __restrict__ bias, float* __restrict__ part)
{
    __shared__ __align__(16) short Abuf[INROWS_A][ACOLS][8];
    __shared__ float red[4][NG][2];
    const int strip = blockIdx.x, b = blockIdx.y;
    const int tid = threadIdx.x, wave = tid >> 6, lane = tid & 63;
    const int i = lane & 15, g = lane >> 4;
    const int r0 = strip * ROWS_A;

    // B fragments into registers (12 x 16B)
    short8v bq[3][4];
    {
        const i32x4* bp = (const i32x4*)Bpack;
        #pragma unroll
        for (int dx = 0; dx < 3; ++dx)
            #pragma unroll
            for (int nt = 0; nt < 4; ++nt) {
                i32x4 v = bp[(dx * 4 + nt) * 64 + lane];
                bq[dx][nt] = *(short8v*)&v;
            }
    }
    float bs[4];
    #pragma unroll
    for (int nt = 0; nt < 4; ++nt) bs[nt] = bias[nt * 16 + i];

    // build Abuf[row][col][cin] (bf16), zero-padded
    {
        const float* xb = x + (size_t)b * CIN * HW * HW;
        for (int e = tid; e < INROWS_A * ACOLS; e += 256) {
            int row = e / ACOLS, col = e % ACOLS;
            int ri = r0 + row;
            bool ok = (row < 10) && (ri < HW) && (col < HW);
            unsigned pk0, pk1, pk2, pk3;
            {
                const float* base = &xb[(size_t)ri * HW + col];
                float v0 = ok ? base[0 * HW * HW] : 0.f;
                float v1 = ok ? base[1 * HW * HW] : 0.f;
                float v2 = ok ? base[2 * HW * HW] : 0.f;
                float v3 = ok ? base[3 * HW * HW] : 0.f;
                float v4 = ok ? base[4 * HW * HW] : 0.f;
                float v5 = ok ? base[5 * HW * HW] : 0.f;
                float v6 = ok ? base[6 * HW * HW] : 0.f;
                float v7 = ok ? base[7 * HW * HW] : 0.f;
                pk0 = (unsigned)(unsigned short)f2bf(v0) | ((unsigned)(unsigned short)f2bf(v1) << 16);
                pk1 = (unsigned)(unsigned short)f2bf(v2) | ((unsigned)(unsigned short)f2bf(v3) << 16);
                pk2 = (unsigned)(unsigned short)f2bf(v4) | ((unsigned)(unsigned short)f2bf(v5) << 16);
                pk3 = (unsigned)(unsigned short)f2bf(v6) | ((unsigned)(unsigned short)f2bf(v7) << 16);
            }
            uint4 w4 = make_uint4(pk0, pk1, pk2, pk3);
            *(uint4*)&Abuf[row][col][0] = w4;
        }
    }
    __syncthreads();

    float s1[4] = {0.f, 0.f, 0.f, 0.f}, s2[4] = {0.f, 0.f, 0.f, 0.f};
    #pragma unroll
    for (int rr = 0; rr < 2; ++rr) {
        const int rloc = wave + rr * 4;
        const int R = r0 + rloc;
        if (R < OHW) {
            for (int t = 0; t < 8; ++t) {
                f32x4 acc[4];
                #pragma unroll
                for (int nt = 0; nt < 4; ++nt) acc[nt] = (f32x4){0.f, 0.f, 0.f, 0.f};
                #pragma unroll
                for (int dx = 0; dx < 3; ++dx) {
                    short8v a = *(const short8v*)&Abuf[rloc + g][16 * t + i + dx][0];
                    #pragma unroll
                    for (int nt = 0; nt < 4; ++nt)
                        acc[nt] = __builtin_amdgcn_mfma_f32_16x16x32_bf16(a, bq[dx][nt], acc[nt], 0, 0, 0);
                }
                const int nv = (t == 7 && g == 3) ? 2 : 4;  // cols >=126 invalid
                #pragma unroll
                for (int nt = 0; nt < 4; ++nt)
                    #pragma unroll
                    for (int r = 0; r < 4; ++r)
                        if (r < nv) {
                            float v = acc[nt][r] + bs[nt];
                            s1[nt] += v;
                            s2[nt] = fmaf(v, v, s2[nt]);
                        }
            }
        }
    }

    // reduce over m (g: xor 16,32) and over group-quad channels (i&3: xor 1,2)
    #pragma unroll
    for (int nt = 0; nt < 4; ++nt) {
        s1[nt] += __shfl_xor(s1[nt], 1);  s1[nt] += __shfl_xor(s1[nt], 2);
        s1[nt] += __shfl_xor(s1[nt], 16); s1[nt] += __shfl_xor(s1[nt], 32);
        s2[nt] += __shfl_xor(s2[nt], 1);  s2[nt] += __shfl_xor(s2[nt], 2);
        s2[nt] += __shfl_xor(s2[nt], 16); s2[nt] += __shfl_xor(s2[nt], 32);
    }
    if (g == 0 && (i & 3) == 0) {
        #pragma unroll
        for (int nt = 0; nt < 4; ++nt) {
            red[wave][nt * 4 + (i >> 2)][0] = s1[nt];
            red[wave][nt * 4 + (i >> 2)][1] = s2[nt];
        }
    }
    __syncthreads();
    if (tid < 32) {
        int grp = tid >> 1, which = tid & 1;
        float v = red[0][grp][which] + red[1][grp][which] + red[2][grp][which] + red[3][grp][which];
        part[(((size_t)b * STRIPS_A + strip) * NG + grp) * 2 + which] = v;
    }
}

// ---- fold stats into per-(b,c) affine: A, B2 (bias folded in) ----
__global__ __launch_bounds__(256) void finalize_stats(
    const float* __restrict__ part, const float* __restrict__ gnw,
    const float* __restrict__ gnb, const float* __restrict__ scale,
    const float* __restrict__ bias, float* __restrict__ Aarr, float* __restrict__ B2arr)
{
    int t = blockIdx.x * 256 + threadIdx.x;
    if (t >= BATCH * NG) return;
    int b = t >> 4, grp = t & 15;
    float s1 = 0.f, s2 = 0.f;
    for (int s = 0; s < STRIPS_A; ++s) {
        s1 += part[(((size_t)b * STRIPS_A + s) * NG + grp) * 2 + 0];
        s2 += part[(((size_t)b * STRIPS_A + s) * NG + grp) * 2 + 1];
    }
    const float invN = 1.f / (float)(4 * OHW * OHW);
    float mean = s1 * invN;
    float var = s2 * invN - mean * mean;
    float rstd = rsqrtf(var + GN_EPS);
    #pragma unroll
    for (int ci = 0; ci < 4; ++ci) {
        int c = grp * 4 + ci;
        float A = rstd * gnw[c] * scale[c];
        float Bv = (gnb[c] - mean * rstd * gnw[c]) * scale[c];
        Aarr[b * COUT + c] = A;
        B2arr[b * COUT + c] = Bv + bias[c] * A;
    }
}

// ---- pass B: bf16-MFMA conv + affine + maxpool + clamp ----
__global__ __launch_bounds__(256, 3) void conv_pool(
    const float* __restrict__ x, const short* __restrict__ Bpack,
    const float* __restrict__ Aarr, const float* __restrict__ B2arr,
    float* __restrict__ out)
{
    __shared__ __align__(16) short Abuf[INROWS_B][ACOLS][8];
    __shared__ float pooled[4][COUT][33];
    const int prow = blockIdx.x, b = blockIdx.y;
    const int tid = threadIdx.x, wave = tid >> 6, lane = tid & 63;
    const int i = lane & 15, g = lane >> 4;
    const int r0 = prow * 4;

    short8v bq[3][4];
    {
        const i32x4* bp = (const i32x4*)Bpack;
        #pragma unroll
        for (int dx = 0; dx < 3; ++dx)
            #pragma unroll
            for (int nt = 0; nt < 4; ++nt) {
                i32x4 v = bp[(dx * 4 + nt) * 64 + lane];
                bq[dx][nt] = *(short8v*)&v;
            }
    }
    float Ac[4], Bc[4];
    #pragma unroll
    for (int nt = 0; nt < 4; ++nt) {
        Ac[nt] = Aarr[b * COUT + nt * 16 + i];
        Bc[nt] = B2arr[b * COUT + nt * 16 + i];
    }

    {
        const float* xb = x + (size_t)b * CIN * HW * HW;
        for (int e = tid; e < INROWS_B * ACOLS; e += 256) {
            int row = e / ACOLS, col = e % ACOLS;
            int ri = r0 + row;
            bool ok = (row < 6) && (col < HW);   // ri <= 125 always for row<6
            unsigned pk0, pk1, pk2, pk3;
            {
                const float* base = &xb[(size_t)ri * HW + col];
                float v0 = ok ? base[0 * HW * HW] : 0.f;
                float v1 = ok ? base[1 * HW * HW] : 0.f;
                float v2 = ok ? base[2 * HW * HW] : 0.f;
                float v3 = ok ? base[3 * HW * HW] : 0.f;
                float v4 = ok ? base[4 * HW * HW] : 0.f;
                float v5 = ok ? base[5 * HW * HW] : 0.f;
                float v6 = ok ? base[6 * HW * HW] : 0.f;
                float v7 = ok ? base[7 * HW * HW] : 0.f;
                pk0 = (unsigned)(unsigned short)f2bf(v0) | ((unsigned)(unsigned short)f2bf(v1) << 16);
                pk1 = (unsigned)(unsigned short)f2bf(v2) | ((unsigned)(unsigned short)f2bf(v3) << 16);
                pk2 = (unsigned)(unsigned short)f2bf(v4) | ((unsigned)(unsigned short)f2bf(v5) << 16);
                pk3 = (unsigned)(unsigned short)f2bf(v6) | ((unsigned)(unsigned short)f2bf(v7) << 16);
            }
            uint4 w4 = make_uint4(pk0, pk1, pk2, pk3);
            *(uint4*)&Abuf[row][col][0] = w4;
        }
    }
    __syncthreads();

    const int rloc = wave;  // conv row r0+wave
    for (int t = 0; t < 8; ++t) {
        f32x4 acc[4];
        #pragma unroll
        for (int nt = 0; nt < 4; ++nt) acc[nt] = (f32x4){0.f, 0.f, 0.f, 0.f};
        #pragma unroll
        for (int dx = 0; dx < 3; ++dx) {
            short8v a = *(const short8v*)&Abuf[rloc + g][16 * t + i + dx][0];
            #pragma unroll
            for (int nt = 0; nt < 4; ++nt)
                acc[nt] = __builtin_amdgcn_mfma_f32_16x16x32_bf16(a, bq[dx][nt], acc[nt], 0, 0, 0);
        }
        const int pc = 4 * t + g;  // pool column = cols 4pc..4pc+3
        #pragma unroll
        for (int nt = 0; nt < 4; ++nt) {
            float v0 = fmaf(acc[nt][0], Ac[nt], Bc[nt]);
            float v1 = fmaf(acc[nt][1], Ac[nt], Bc[nt]);
            float v2 = fmaf(acc[nt][2], Ac[nt], Bc[nt]);
            float v3 = fmaf(acc[nt][3], Ac[nt], Bc[nt]);
            float m = fmaxf(fmaxf(v0, v1), fmaxf(v2, v3));
            if (pc < PH) pooled[wave][nt * 16 + i][pc] = m;
        }
    }
    __syncthreads();

    // cross-row max + clamp + coalesced-ish write (31 contiguous f32 per channel)
    for (int cc = 0; cc < 16; ++cc) {
        int c = wave * 16 + cc;
        if (lane < PH) {
            float m = fmaxf(fmaxf(pooled[0][c][lane], pooled[1][c][lane]),
                            fmaxf(pooled[2][c][lane], pooled[3][c][lane]));
            m = fminf(fmaxf(m, 0.f), 1.f);
            out[((size_t)(b * COUT + c) * PH + prow) * PH + lane] = m;
        }
    }
}

extern "C" void kernel_launch(void* const* d_in, const int* in_sizes, int n_in,
                              void* d_out, int out_size, void* d_ws, size_t ws_size,
                              hipStream_t stream)
{
    const float* x   = (const float*)d_in[0];
    const float* w   = (const float*)d_in[1];
    const float* cbv = (const float*)d_in[2];
    const float* gnw = (const float*)d_in[3];
    const float* gnb = (const float*)d_in[4];
    const float* sc  = (const float*)d_in[5];
    float* out = (float*)d_out;

    float* part  = (float*)d_ws;                 // 128*16*16*2 = 65536 f32
    float* Aarr  = part + 65536;                 // 8192 f32
    float* B2arr = Aarr + 8192;                  // 8192 f32
    short* Bpack = (short*)(B2arr + 8192);       // 3*4*64*8 = 6144 bf16

    prep_weights<<<dim3(1), 256, 0, stream>>>(w, Bpack);
    conv_stats<<<dim3(STRIPS_A, BATCH), 256, 0, stream>>>(x, Bpack, cbv, part);
    finalize_stats<<<dim3(8), 256, 0, stream>>>(part, gnw, gnb, sc, cbv, Aarr, B2arr);
    conv_pool<<<dim3(PH, BATCH), 256, 0, stream>>>(x, Bpack, Aarr, B2arr, out);
}